// Round 4
// baseline (237.894 us; speedup 1.0000x reference)
//
#include <hip/hip_runtime.h>

// Problem constants (from reference setup_inputs):
//   fm0: [16,3,80,80,85]: 26,112,000 floats = 6,528,000 f4, 19200 rows/b, scale 80
//   fm1: [16,3,40,40,85]:  6,528,000 floats = 1,632,000 f4,  4800 rows/b, scale 40
//   fm2: [16,3,20,20,85]:  1,632,000 floats =   408,000 f4,  1200 rows/b, scale 20
//   out: [16, 25200, 85]
#define NROWS_OUT 25200

// Blocks of 512 float4s (256 threads x 2):
//   L0: 6,528,000/512 = 12750 (exact)
//   L1: 1,632,000/512 = 3187.5 -> 3188 (last block half-active)
//   L2:   408,000/512 =  796.875 -> 797
#define L0_BLOCKS 12750
#define L1_BLOCKS 3188
#define L2_BLOCKS 797
#define TOTAL_BLOCKS (L0_BLOCKS + L1_BLOCKS + L2_BLOCKS)   // 16735

typedef float v4f __attribute__((ext_vector_type(4)));

__device__ __forceinline__ float fast_sigmoid(float x) {
    // v_exp_f32 + v_rcp_f32; rel err ~1e-6 (absmax tolerance already passes).
    return __builtin_amdgcn_rcpf(1.0f + __expf(-x));
}

// Process one float4 (level-local float4 index v, data x already in regs).
// Box-row floats come from LDS (staged by this block, incl. halo).
template <int ROWS, int OFF, int SCALE>
__device__ __forceinline__ void emit4(float* __restrict__ out,
                                      const float* __restrict__ ldsf,
                                      int basef, int v, v4f x) {
    const int f = v * 4;                       // level-local float index
    constexpr int ROWS85 = ROWS * 85;
    const int b   = f / ROWS85;                // magic-mul (const divisor)
    const int rem = f - b * ROWS85;
    const int c0  = rem % 85;

    // Row start (level-local float idx); dummy = own addr when no box here.
    int g = f;
    if (c0 <= 3)  g = f - c0;                  // row begins at/just before us
    if (c0 >= 82) g = f + (85 - c0);           // next row begins inside us
    // LDS covers floats [basef-4, basef+2052); g in [f-3, f+3], g+3 in range.
    const int lo = g - basef + 4;
    const float r0 = ldsf[lo + 0];
    const float r1 = ldsf[lo + 1];
    const float r2 = ldsf[lo + 2];
    const float r3 = ldsf[lo + 3];

    const float sc = (float)SCALE;
    const float h2 = 0.5f * r2, h3 = 0.5f * r3;
    const float q0 = (r0 - h2) * sc;           // x1
    const float q1 = (r1 - h3) * sc;           // y1
    const float q2 = (q0 + h2) * sc;           // x2
    const float q3 = (q1 + h3) * sc;           // y2

    float xv[4] = {x.x, x.y, x.z, x.w};
    float y[4];
#pragma unroll
    for (int k = 0; k < 4; ++k) {
        int c = c0 + k;
        if (c >= 85) c -= 85;                  // at most one row wrap
        const float s = fast_sigmoid(xv[k]);
        const float q = (c == 0) ? q0 : ((c == 1) ? q1 : ((c == 2) ? q2 : q3));
        y[k] = (c < 4) ? q : s;                // cndmask chain, no branch
    }

    const int out_f = (b * NROWS_OUT + OFF) * 85 + rem;  // multiple of 4 (proof in notes)
    v4f yo; yo.x = y[0]; yo.y = y[1]; yo.z = y[2]; yo.w = y[3];
    __builtin_nontemporal_store(yo, (v4f*)(out + out_f));
}

// One block handles 512 contiguous float4s of one level, staged through LDS
// with a 1-float4 halo each side so box rows never need global re-reads.
template <int ROWS, int OFF, int SCALE, int NF4>
__device__ __forceinline__ void run_level(const float* __restrict__ in,
                                          float* __restrict__ out,
                                          v4f* __restrict__ lds4, int bb) {
    const int t     = threadIdx.x;
    const int base4 = bb * 512;
    const int basef = base4 * 4;

    const int v1 = base4 + t;
    const int v2 = base4 + 256 + t;
    const bool a1 = v1 < NF4;
    const bool a2 = v2 < NF4;

    v4f x1, x2;
    if (a1) { x1 = *(const v4f*)(in + v1 * 4); lds4[1 + t]   = x1; }
    if (a2) { x2 = *(const v4f*)(in + v2 * 4); lds4[257 + t] = x2; }
    // Halo (clamped; clamp only engages where the halo is provably unused:
    // levels start/end on row boundaries, so rows never cross level edges).
    if (t == 0) {
        int hv = base4 - 1; if (hv < 0) hv = 0;
        lds4[0] = *(const v4f*)(in + hv * 4);
    }
    if (t == 255) {
        int hv = base4 + 512; if (hv > NF4 - 1) hv = NF4 - 1;
        lds4[513] = *(const v4f*)(in + hv * 4);
    }
    __syncthreads();

    const float* ldsf = (const float*)lds4;
    if (a1) emit4<ROWS, OFF, SCALE>(out, ldsf, basef, v1, x1);
    if (a2) emit4<ROWS, OFF, SCALE>(out, ldsf, basef, v2, x2);
}

__global__ __launch_bounds__(256) void yolo_decode_kernel(
    const float* __restrict__ fm0, const float* __restrict__ fm1,
    const float* __restrict__ fm2, float* __restrict__ out) {
    __shared__ v4f lds4[514];                  // 8224 B, shared across levels
    const int bb = blockIdx.x;
    if (bb < L0_BLOCKS) {
        run_level<19200, 0, 80, 6528000>(fm0, out, lds4, bb);
    } else if (bb < L0_BLOCKS + L1_BLOCKS) {
        run_level<4800, 19200, 40, 1632000>(fm1, out, lds4, bb - L0_BLOCKS);
    } else {
        run_level<1200, 24000, 20, 408000>(fm2, out, lds4,
                                           bb - (L0_BLOCKS + L1_BLOCKS));
    }
}

extern "C" void kernel_launch(void* const* d_in, const int* in_sizes, int n_in,
                              void* d_out, int out_size, void* d_ws, size_t ws_size,
                              hipStream_t stream) {
    const float* fm0 = (const float*)d_in[0];
    const float* fm1 = (const float*)d_in[1];
    const float* fm2 = (const float*)d_in[2];
    float* out = (float*)d_out;

    hipLaunchKernelGGL(yolo_decode_kernel, dim3(TOTAL_BLOCKS), dim3(256), 0,
                       stream, fm0, fm1, fm2, out);
}